// Round 4
// baseline (264.082 us; speedup 1.0000x reference)
//
#include <hip/hip_runtime.h>
#include <hip/hip_bf16.h>

// ENN_20203526160942 — R4: fused main kernel (pairs+post+finish), x2-split f16 MFMA,
// prescaled-by-2log2(e) tanh domain, r-sum trick.  (R3 + cvt_pkrtz type fix)
//
// Stage 1 (k_prep): H = LM[cat]; preI = c*(H@W1i); P3 = pack(c*(H@W1j + be1)) in MFMA
//                   A-frag order; zero out[0].  (c = 2*log2(e))
// Stage 2 (k_main): block i:
//   V[i] = 65472 - 2 * sum_{j!=i,l} 1/(exp2(c*(S+be2))+1),  S = tanh(h1) @ We2 via MFMA
//   then newH[i] = tanh(tanh(H[i]@Wh1[:64] + V*Wh1[64] + bh1)@Wh2 + bh2)
//   atomicAdd(out, newH[i]@Wo (+ bo for i==0))

#define N_ATOMS 1024
#define L_DIM 64
#define TPB 256
#define CSCALE 2.8853900817779268f   // 2*log2(e)

typedef _Float16 f16x8 __attribute__((ext_vector_type(8)));
typedef __fp16  fp16x2 __attribute__((ext_vector_type(2)));
typedef float f32x4 __attribute__((ext_vector_type(4)));

__device__ __forceinline__ float tanh_fast(float x) {
    float e = __builtin_amdgcn_exp2f(x * CSCALE);
    float r = __builtin_amdgcn_rcpf(e + 1.0f);
    return fmaf(-2.0f, r, 1.0f);
}

// ---------------- Stage 1: prep ----------------
__global__ __launch_bounds__(256) void k_prep(const int* __restrict__ cat,
                                              const float* __restrict__ LM,
                                              const float* __restrict__ We1,
                                              const float* __restrict__ be1,
                                              float* __restrict__ H,
                                              float* __restrict__ preI,
                                              float* __restrict__ P3,
                                              float* __restrict__ out) {
    int t = threadIdx.x;
    int sub = t >> 6, l = t & 63;
    int i = blockIdx.x * 4 + sub;
    if (blockIdx.x == 0 && t == 0) out[0] = 0.f;   // harness poisons d_out each call
    __shared__ float hrow[4][L_DIM];
    float hv = LM[cat[i] * L_DIM + l];
    hrow[sub][l] = hv;
    H[i * L_DIM + l] = hv;
    __syncthreads();
    float s1 = 0.f, s2 = 0.f;
#pragma unroll
    for (int m = 0; m < L_DIM; m++) {
        float h = hrow[sub][m];
        s1 = fmaf(h, We1[m * L_DIM + l], s1);
        s2 = fmaf(h, We1[(L_DIM + m) * L_DIM + l], s2);
    }
    preI[i * L_DIM + l] = s1 * CSCALE;
    // pack c*(prejb) into A-fragment order (mapping verified in R2):
    int cc = i >> 4;
    int Ll = i & 15;
    int quad = (l >> 3) & 3;
    int L = quad * 16 + Ll;
    int g = ((l >> 5) << 1) | ((l >> 2) & 1);
    int e2 = l & 3;
    P3[cc * 1024 + g * 256 + L * 4 + e2] = (s2 + be1[l]) * CSCALE;
}

// ---------------- Stage 2: fused main ----------------
__global__ __launch_bounds__(TPB, 6) void k_main(const float* __restrict__ Z,
                                                 const float* __restrict__ We1,
                                                 const float* __restrict__ We2,
                                                 const float* __restrict__ be2,
                                                 const float* __restrict__ preI,
                                                 const float* __restrict__ P3,
                                                 const float* __restrict__ H,
                                                 const float* __restrict__ Wh1,
                                                 const float* __restrict__ bh1,
                                                 const float* __restrict__ Wh2,
                                                 const float* __restrict__ bh2,
                                                 const float* __restrict__ Wo,
                                                 const float* __restrict__ bo,
                                                 float* __restrict__ out) {
    int i = blockIdx.x;
    int t = threadIdx.x;
    int lane = t & 63;
    int wave = t >> 6;
    int nlo = lane & 15;
    int quad = lane >> 4;

    __shared__ float d2s[N_ATOMS];
    __shared__ float red[TPB];
    __shared__ float hrow_s[L_DIM];
    __shared__ float hh_s[L_DIM];

    // d2 table for this i
    float zi0 = Z[i * 3], zi1 = Z[i * 3 + 1], zi2 = Z[i * 3 + 2];
    for (int p = t; p < N_ATOMS; p += TPB) {
        float a = zi0 - Z[p * 3], b = zi1 - Z[p * 3 + 1], c = zi2 - Z[p * 3 + 2];
        d2s[p] = a * a + b * b + c * c;
    }

    // per-lane constants (preI already prescaled; scale w1z/be2 here)
    f32x4 aiR[4], wzR[4];
#pragma unroll
    for (int g = 0; g < 4; g++) {
        int mb = ((g >> 1) << 5) + (quad << 3) + ((g & 1) << 2);
        aiR[g] = *(const f32x4*)(preI + i * L_DIM + mb);
        f32x4 wz = *(const f32x4*)(We1 + 2 * L_DIM * L_DIM + mb);
        wzR[g] = wz * CSCALE;
    }
    float be2R[4];
#pragma unroll
    for (int nt = 0; nt < 4; nt++) be2R[nt] = be2[nt * 16 + nlo] * CSCALE;

    // B fragments (c*We2, hi/lo f16 split), register resident
    f16x8 bH[4][2], bL[4][2];
#pragma unroll
    for (int nt = 0; nt < 4; nt++)
#pragma unroll
        for (int kt = 0; kt < 2; kt++)
#pragma unroll
            for (int e = 0; e < 8; e++) {
                float w = We2[(kt * 32 + quad * 8 + e) * L_DIM + nt * 16 + nlo] * CSCALE;
                _Float16 hi = (_Float16)w;
                bH[nt][kt][e] = hi;
                bL[nt][kt][e] = (_Float16)(w - (float)hi);
            }
    __syncthreads();

    float Vr = 0.f;   // sum of 1/(exp2(arg)+1)
    const float* Pbase = P3 + wave * 16 * 1024 + lane * 4;

    f32x4 p0 = *(const f32x4*)(Pbase + 0 * 256);
    f32x4 p1 = *(const f32x4*)(Pbase + 1 * 256);
    f32x4 p2 = *(const f32x4*)(Pbase + 2 * 256);
    f32x4 p3 = *(const f32x4*)(Pbase + 3 * 256);

    for (int k = 0; k < 16; k++) {
        int j0 = (wave * 16 + k) * 16;
        float d2 = d2s[j0 + nlo];

        // h1 tile (A-layout row j0+nlo), f16 A (hi only)
        float h[4][4];
#pragma unroll
        for (int e2 = 0; e2 < 4; e2++) {
            {
                float z = fmaf(d2, wzR[0][e2], aiR[0][e2] + p0[e2]);
                float e = __builtin_amdgcn_exp2f(z);
                float r = __builtin_amdgcn_rcpf(e + 1.0f);
                h[0][e2] = fmaf(-2.0f, r, 1.0f);
            }
            {
                float z = fmaf(d2, wzR[1][e2], aiR[1][e2] + p1[e2]);
                float e = __builtin_amdgcn_exp2f(z);
                float r = __builtin_amdgcn_rcpf(e + 1.0f);
                h[1][e2] = fmaf(-2.0f, r, 1.0f);
            }
            {
                float z = fmaf(d2, wzR[2][e2], aiR[2][e2] + p2[e2]);
                float e = __builtin_amdgcn_exp2f(z);
                float r = __builtin_amdgcn_rcpf(e + 1.0f);
                h[2][e2] = fmaf(-2.0f, r, 1.0f);
            }
            {
                float z = fmaf(d2, wzR[3][e2], aiR[3][e2] + p3[e2]);
                float e = __builtin_amdgcn_exp2f(z);
                float r = __builtin_amdgcn_rcpf(e + 1.0f);
                h[3][e2] = fmaf(-2.0f, r, 1.0f);
            }
        }
        union { f16x8 v; fp16x2 h2[4]; } u0, u1;
        u0.h2[0] = __builtin_amdgcn_cvt_pkrtz(h[0][0], h[0][1]);
        u0.h2[1] = __builtin_amdgcn_cvt_pkrtz(h[0][2], h[0][3]);
        u0.h2[2] = __builtin_amdgcn_cvt_pkrtz(h[1][0], h[1][1]);
        u0.h2[3] = __builtin_amdgcn_cvt_pkrtz(h[1][2], h[1][3]);
        u1.h2[0] = __builtin_amdgcn_cvt_pkrtz(h[2][0], h[2][1]);
        u1.h2[1] = __builtin_amdgcn_cvt_pkrtz(h[2][2], h[2][3]);
        u1.h2[2] = __builtin_amdgcn_cvt_pkrtz(h[3][0], h[3][1]);
        u1.h2[3] = __builtin_amdgcn_cvt_pkrtz(h[3][2], h[3][3]);
        f16x8 aH0 = u0.v, aH1 = u1.v;

        // prefetch next chunk's packed prejb
        if (k < 15) {
            const float* nb = Pbase + (k + 1) * 1024;
            p0 = *(const f32x4*)(nb + 0 * 256);
            p1 = *(const f32x4*)(nb + 1 * 256);
            p2 = *(const f32x4*)(nb + 2 * 256);
            p3 = *(const f32x4*)(nb + 3 * 256);
        }

        // S' = c*(h1@We2 + be2) via MFMA (bias folded into acc init), then r-sum
#pragma unroll
        for (int nt = 0; nt < 4; nt++) {
            f32x4 acc = {be2R[nt], be2R[nt], be2R[nt], be2R[nt]};
            acc = __builtin_amdgcn_mfma_f32_16x16x32_f16(aH0, bH[nt][0], acc, 0, 0, 0);
            acc = __builtin_amdgcn_mfma_f32_16x16x32_f16(aH0, bL[nt][0], acc, 0, 0, 0);
            acc = __builtin_amdgcn_mfma_f32_16x16x32_f16(aH1, bH[nt][1], acc, 0, 0, 0);
            acc = __builtin_amdgcn_mfma_f32_16x16x32_f16(aH1, bL[nt][1], acc, 0, 0, 0);
#pragma unroll
            for (int r4 = 0; r4 < 4; r4++) {
                int jg = j0 + quad * 4 + r4;
                float e = __builtin_amdgcn_exp2f(acc[r4]);
                float rr = __builtin_amdgcn_rcpf(e + 1.0f);
                Vr += (jg != i) ? rr : 0.f;
            }
        }
    }

    red[t] = Vr;
    __syncthreads();

    // ---- post + finish for atom i (wave 0) ----
    float V;
    if (t < 64) {
        float r = red[t] + red[t + 64] + red[t + 128] + red[t + 192];
#pragma unroll
        for (int o = 32; o > 0; o >>= 1) r += __shfl_xor(r, o);
        V = fmaf(-2.0f, r, (float)(1023 * L_DIM));
        hrow_s[t] = H[i * L_DIM + t];
    }
    __syncthreads();
    if (t < 64) {
        float s = 0.f;
#pragma unroll
        for (int m = 0; m < L_DIM; m++) s = fmaf(hrow_s[m], Wh1[m * L_DIM + t], s);
        s = fmaf(V, Wh1[L_DIM * L_DIM + t], s) + bh1[t];
        hh_s[t] = tanh_fast(s);
    }
    __syncthreads();
    if (t < 64) {
        float s2 = 0.f;
#pragma unroll
        for (int m = 0; m < L_DIM; m++) s2 = fmaf(hh_s[m], Wh2[m * L_DIM + t], s2);
        float nh = tanh_fast(s2 + bh2[t]);
        float w = nh * Wo[t];
#pragma unroll
        for (int o = 32; o > 0; o >>= 1) w += __shfl_down(w, o);
        if (t == 0) atomicAdd(out, w + (i == 0 ? bo[0] : 0.f));
    }
}

extern "C" void kernel_launch(void* const* d_in, const int* in_sizes, int n_in,
                              void* d_out, int out_size, void* d_ws, size_t ws_size,
                              hipStream_t stream) {
    const int*   cat = (const int*)  d_in[0];
    const float* Z   = (const float*)d_in[1];
    const float* LM  = (const float*)d_in[2];
    const float* We1 = (const float*)d_in[3];
    const float* be1 = (const float*)d_in[4];
    const float* We2 = (const float*)d_in[5];
    const float* be2 = (const float*)d_in[6];
    const float* Wh1 = (const float*)d_in[7];
    const float* bh1 = (const float*)d_in[8];
    const float* Wh2 = (const float*)d_in[9];
    const float* bh2 = (const float*)d_in[10];
    const float* Wo  = (const float*)d_in[11];
    const float* bo  = (const float*)d_in[12];
    float* out = (float*)d_out;

    float* ws   = (float*)d_ws;
    float* H    = ws;                       // 1024*64
    float* preI = H    + N_ATOMS * L_DIM;   // 1024*64 (prescaled)
    float* P3   = preI + N_ATOMS * L_DIM;   // 1024*64 (packed, prescaled)

    k_prep<<<N_ATOMS / 4, 256, 0, stream>>>(cat, LM, We1, be1, H, preI, P3, out);
    k_main<<<N_ATOMS, TPB, 0, stream>>>(Z, We1, We2, be2, preI, P3, H,
                                        Wh1, bh1, Wh2, bh2, Wo, bo, out);
}

// Round 5
// 121.628 us; speedup vs baseline: 2.1712x; 2.1712x over previous
//
#include <hip/hip_runtime.h>
#include <hip/hip_bf16.h>

// ENN_20203526160942 — R5: fused kernel, r-fed MFMA (bias-folded colsum), bL in LDS,
// diagonal subtracted once per block, NO forced occupancy cap (R4's spill bug).
//
// k_prep: H = LM[cat]; preI = c*(H@W1i); P3 = pack(c*(H@W1j + be1)); zero out.
// k_main (block i):
//   r[j,m] = 1/(exp2(z)+1), z = preI_i[m] + P3_j[m] + d2_ij*(c*w1z[m])
//   S'(j,l) = c*(tanh(h1)@We2 + be2)[l] = bias_l + r @ (-2c*We2)  via f16 MFMA (hi/lo split)
//   Rall = sum_{all j,l} 1/(exp2(S')+1);  V = 65472 - 2*(Rall - Rdiag)
//   then newH/out epilogue (atomicAdd).

#define N_ATOMS 1024
#define L_DIM 64
#define TPB 256
#define CSCALE 2.8853900817779268f   // 2*log2(e)

typedef _Float16 f16x8 __attribute__((ext_vector_type(8)));
typedef __fp16  fp16x2 __attribute__((ext_vector_type(2)));
typedef float f32x4 __attribute__((ext_vector_type(4)));

__device__ __forceinline__ float tanh_fast(float x) {
    float e = __builtin_amdgcn_exp2f(x * CSCALE);
    float r = __builtin_amdgcn_rcpf(e + 1.0f);
    return fmaf(-2.0f, r, 1.0f);
}

// ---------------- Stage 1: prep ----------------
__global__ __launch_bounds__(256) void k_prep(const int* __restrict__ cat,
                                              const float* __restrict__ LM,
                                              const float* __restrict__ We1,
                                              const float* __restrict__ be1,
                                              float* __restrict__ H,
                                              float* __restrict__ preI,
                                              float* __restrict__ P3,
                                              float* __restrict__ out) {
    int t = threadIdx.x;
    int sub = t >> 6, l = t & 63;
    int i = blockIdx.x * 4 + sub;
    if (blockIdx.x == 0 && t == 0) out[0] = 0.f;
    __shared__ float hrow[4][L_DIM];
    float hv = LM[cat[i] * L_DIM + l];
    hrow[sub][l] = hv;
    H[i * L_DIM + l] = hv;
    __syncthreads();
    float s1 = 0.f, s2 = 0.f;
#pragma unroll
    for (int m = 0; m < L_DIM; m++) {
        float h = hrow[sub][m];
        s1 = fmaf(h, We1[m * L_DIM + l], s1);
        s2 = fmaf(h, We1[(L_DIM + m) * L_DIM + l], s2);
    }
    preI[i * L_DIM + l] = s1 * CSCALE;
    // pack c*(prejb) into A-fragment order (verified R2/R4):
    int cc = i >> 4;
    int Ll = i & 15;
    int quad = (l >> 3) & 3;
    int L = quad * 16 + Ll;
    int g = ((l >> 5) << 1) | ((l >> 2) & 1);
    int e2 = l & 3;
    P3[cc * 1024 + g * 256 + L * 4 + e2] = (s2 + be1[l]) * CSCALE;
}

// ---------------- Stage 2: fused main ----------------
__global__ __launch_bounds__(TPB) void k_main(const float* __restrict__ Z,
                                              const float* __restrict__ We1,
                                              const float* __restrict__ We2,
                                              const float* __restrict__ be2,
                                              const float* __restrict__ preI,
                                              const float* __restrict__ P3,
                                              const float* __restrict__ H,
                                              const float* __restrict__ Wh1,
                                              const float* __restrict__ bh1,
                                              const float* __restrict__ Wh2,
                                              const float* __restrict__ bh2,
                                              const float* __restrict__ Wo,
                                              const float* __restrict__ bo,
                                              float* __restrict__ out) {
    int i = blockIdx.x;
    int t = threadIdx.x;
    int lane = t & 63;
    int wave = t >> 6;
    int nlo = lane & 15;
    int quad = lane >> 4;

    __shared__ float d2s[N_ATOMS];
    __shared__ float red[TPB];
    __shared__ float hrow_s[L_DIM];
    __shared__ float hh_s[L_DIM];
    __shared__ float dgt[L_DIM];
    __shared__ f16x8 bLs[8 * 64];   // 8 KB: [(kt*4+nt)*64 + lane]

    // d2 table for this i
    float zi0 = Z[i * 3], zi1 = Z[i * 3 + 1], zi2 = Z[i * 3 + 2];
    for (int p = t; p < N_ATOMS; p += TPB) {
        float a = zi0 - Z[p * 3], b = zi1 - Z[p * 3 + 1], c = zi2 - Z[p * 3 + 2];
        d2s[p] = a * a + b * b + c * c;
    }

    // per-lane constants
    f32x4 aiR[4], wzR[4];
#pragma unroll
    for (int g = 0; g < 4; g++) {
        int mb = ((g >> 1) << 5) + (quad << 3) + ((g & 1) << 2);
        aiR[g] = *(const f32x4*)(preI + i * L_DIM + mb);
        f32x4 wz = *(const f32x4*)(We1 + 2 * L_DIM * L_DIM + mb);
        wzR[g] = wz * CSCALE;
    }

    // B fragments: B' = -2c*We2; hi in regs, lo to LDS (wave 0 writes).
    // Also column sums for the bias fold.
    f16x8 bH[4][2];
    float biasR[4];
#pragma unroll
    for (int nt = 0; nt < 4; nt++) {
        float psum = 0.f;
#pragma unroll
        for (int kt = 0; kt < 2; kt++) {
            f16x8 hi8, lo8;
#pragma unroll
            for (int e = 0; e < 8; e++) {
                float x = We2[(kt * 32 + quad * 8 + e) * L_DIM + nt * 16 + nlo];
                psum += x;
                float wp = -2.0f * CSCALE * x;
                _Float16 hi = (_Float16)wp;
                hi8[e] = hi;
                lo8[e] = (_Float16)(wp - (float)hi);
            }
            bH[nt][kt] = hi8;
            if (wave == 0) bLs[(kt * 4 + nt) * 64 + lane] = lo8;
        }
        psum += __shfl_xor(psum, 16);
        psum += __shfl_xor(psum, 32);
        biasR[nt] = CSCALE * (be2[nt * 16 + nlo] + psum);
    }

    const float* Pbase = P3 + wave * 16 * 1024 + lane * 4;
    f32x4 p0 = *(const f32x4*)(Pbase + 0 * 256);
    f32x4 p1 = *(const f32x4*)(Pbase + 1 * 256);
    f32x4 p2 = *(const f32x4*)(Pbase + 2 * 256);
    f32x4 p3 = *(const f32x4*)(Pbase + 3 * 256);

    __syncthreads();

    float Vr = 0.f;   // sum over all j,l of 1/(exp2(S')+1)
    for (int k = 0; k < 16; k++) {
        int j0 = (wave * 16 + k) * 16;
        float d2 = d2s[j0 + nlo];

        // A-frag: r = 1/(exp2(z)+1) per element, f16
        float h[4][4];
#pragma unroll
        for (int e2 = 0; e2 < 4; e2++) {
            {
                float z = fmaf(d2, wzR[0][e2], aiR[0][e2] + p0[e2]);
                h[0][e2] = __builtin_amdgcn_rcpf(__builtin_amdgcn_exp2f(z) + 1.0f);
            }
            {
                float z = fmaf(d2, wzR[1][e2], aiR[1][e2] + p1[e2]);
                h[1][e2] = __builtin_amdgcn_rcpf(__builtin_amdgcn_exp2f(z) + 1.0f);
            }
            {
                float z = fmaf(d2, wzR[2][e2], aiR[2][e2] + p2[e2]);
                h[2][e2] = __builtin_amdgcn_rcpf(__builtin_amdgcn_exp2f(z) + 1.0f);
            }
            {
                float z = fmaf(d2, wzR[3][e2], aiR[3][e2] + p3[e2]);
                h[3][e2] = __builtin_amdgcn_rcpf(__builtin_amdgcn_exp2f(z) + 1.0f);
            }
        }
        union { f16x8 v; fp16x2 h2[4]; } u0, u1;
        u0.h2[0] = __builtin_amdgcn_cvt_pkrtz(h[0][0], h[0][1]);
        u0.h2[1] = __builtin_amdgcn_cvt_pkrtz(h[0][2], h[0][3]);
        u0.h2[2] = __builtin_amdgcn_cvt_pkrtz(h[1][0], h[1][1]);
        u0.h2[3] = __builtin_amdgcn_cvt_pkrtz(h[1][2], h[1][3]);
        u1.h2[0] = __builtin_amdgcn_cvt_pkrtz(h[2][0], h[2][1]);
        u1.h2[1] = __builtin_amdgcn_cvt_pkrtz(h[2][2], h[2][3]);
        u1.h2[2] = __builtin_amdgcn_cvt_pkrtz(h[3][0], h[3][1]);
        u1.h2[3] = __builtin_amdgcn_cvt_pkrtz(h[3][2], h[3][3]);
        f16x8 aH0 = u0.v, aH1 = u1.v;

        if (k < 15) {
            const float* nb = Pbase + (k + 1) * 1024;
            p0 = *(const f32x4*)(nb + 0 * 256);
            p1 = *(const f32x4*)(nb + 1 * 256);
            p2 = *(const f32x4*)(nb + 2 * 256);
            p3 = *(const f32x4*)(nb + 3 * 256);
        }

#pragma unroll
        for (int nt = 0; nt < 4; nt++) {
            f16x8 bl0 = bLs[(0 * 4 + nt) * 64 + lane];
            f16x8 bl1 = bLs[(1 * 4 + nt) * 64 + lane];
            f32x4 acc = {biasR[nt], biasR[nt], biasR[nt], biasR[nt]};
            acc = __builtin_amdgcn_mfma_f32_16x16x32_f16(aH0, bH[nt][0], acc, 0, 0, 0);
            acc = __builtin_amdgcn_mfma_f32_16x16x32_f16(aH0, bl0, acc, 0, 0, 0);
            acc = __builtin_amdgcn_mfma_f32_16x16x32_f16(aH1, bH[nt][1], acc, 0, 0, 0);
            acc = __builtin_amdgcn_mfma_f32_16x16x32_f16(aH1, bl1, acc, 0, 0, 0);
#pragma unroll
            for (int r4 = 0; r4 < 4; r4++) {
                float e = __builtin_amdgcn_exp2f(acc[r4]);
                Vr += __builtin_amdgcn_rcpf(e + 1.0f);
            }
        }
    }

    red[t] = Vr;
    __syncthreads();

    // ---- diagonal + post + finish (wave 0) ----
    float Rall;
    if (t < 64) {
        float r = red[t] + red[t + 64] + red[t + 128] + red[t + 192];
#pragma unroll
        for (int o = 32; o > 0; o >>= 1) r += __shfl_xor(r, o);
        Rall = r;
        // diagonal h1 tanh (d2 = 0), m = t
        int cc = i >> 4, Ll = i & 15;
        int q2 = (t >> 3) & 3;
        int g = ((t >> 5) << 1) | ((t >> 2) & 1);
        float z = preI[i * L_DIM + t] + P3[cc * 1024 + g * 256 + (q2 * 16 + Ll) * 4 + (t & 3)];
        float rr = __builtin_amdgcn_rcpf(__builtin_amdgcn_exp2f(z) + 1.0f);
        dgt[t] = fmaf(-2.0f, rr, 1.0f);
        hrow_s[t] = H[i * L_DIM + t];
    }
    __syncthreads();
    if (t < 64) {
        // S_ii(l=t), then Rdiag
        float S = be2[t];
#pragma unroll
        for (int m = 0; m < L_DIM; m++) S = fmaf(dgt[m], We2[m * L_DIM + t], S);
        float rd = __builtin_amdgcn_rcpf(__builtin_amdgcn_exp2f(S * CSCALE) + 1.0f);
#pragma unroll
        for (int o = 32; o > 0; o >>= 1) rd += __shfl_xor(rd, o);
        float V = fmaf(-2.0f, Rall - rd, (float)(1023 * L_DIM));
        float s = 0.f;
#pragma unroll
        for (int m = 0; m < L_DIM; m++) s = fmaf(hrow_s[m], Wh1[m * L_DIM + t], s);
        s = fmaf(V, Wh1[L_DIM * L_DIM + t], s) + bh1[t];
        hh_s[t] = tanh_fast(s);
    }
    __syncthreads();
    if (t < 64) {
        float s2 = 0.f;
#pragma unroll
        for (int m = 0; m < L_DIM; m++) s2 = fmaf(hh_s[m], Wh2[m * L_DIM + t], s2);
        float nh = tanh_fast(s2 + bh2[t]);
        float w = nh * Wo[t];
#pragma unroll
        for (int o = 32; o > 0; o >>= 1) w += __shfl_down(w, o);
        if (t == 0) atomicAdd(out, w + (i == 0 ? bo[0] : 0.f));
    }
}

extern "C" void kernel_launch(void* const* d_in, const int* in_sizes, int n_in,
                              void* d_out, int out_size, void* d_ws, size_t ws_size,
                              hipStream_t stream) {
    const int*   cat = (const int*)  d_in[0];
    const float* Z   = (const float*)d_in[1];
    const float* LM  = (const float*)d_in[2];
    const float* We1 = (const float*)d_in[3];
    const float* be1 = (const float*)d_in[4];
    const float* We2 = (const float*)d_in[5];
    const float* be2 = (const float*)d_in[6];
    const float* Wh1 = (const float*)d_in[7];
    const float* bh1 = (const float*)d_in[8];
    const float* Wh2 = (const float*)d_in[9];
    const float* bh2 = (const float*)d_in[10];
    const float* Wo  = (const float*)d_in[11];
    const float* bo  = (const float*)d_in[12];
    float* out = (float*)d_out;

    float* ws   = (float*)d_ws;
    float* H    = ws;                       // 1024*64
    float* preI = H    + N_ATOMS * L_DIM;   // 1024*64 (c-prescaled)
    float* P3   = preI + N_ATOMS * L_DIM;   // 1024*64 (packed, c-prescaled)

    k_prep<<<N_ATOMS / 4, 256, 0, stream>>>(cat, LM, We1, be1, H, preI, P3, out);
    k_main<<<N_ATOMS, TPB, 0, stream>>>(Z, We1, We2, be2, preI, P3, H,
                                        Wh1, bh1, Wh2, bh2, Wo, bo, out);
}